// Round 10
// baseline (310.530 us; speedup 1.0000x reference)
//
#include <hip/hip_runtime.h>
#include <hip/hip_fp16.h>
#include <math.h>

#define NNODES 50000
#define NEDGES 800000
#define HD     128      // H*D
#define NHEADS 4
#define DH     32

#define TILE_R 64       // gemm rows per block
#define AKPF   136      // full-K padded stride (halves)

// Bucketed CSR build (round-9 lesson: naive 4B random scatter = 17x write amp;
// all fine-grained scatter must happen in LDS).
#define NBUCK  196
#define BCAP   6144
#define P1_T   512
#define P1_EPB 4096
#define P2_T   512

typedef _Float16 f16x8 __attribute__((ext_vector_type(8)));
typedef float    f32x4 __attribute__((ext_vector_type(4)));

static __device__ __forceinline__ float elu(float x){ return x > 0.f ? x : __expf(x) - 1.f; }

// ---------------- CSR build, bucketed ----------------
// btail zeroed via hipMemsetAsync (holds COUNTS). W/Wproj transpose+fp16 folded
// into p1 (round-22).

__global__ __launch_bounds__(P1_T) void p1_bucket_kernel(
    const int* __restrict__ src, const int* __restrict__ dst,
    int* __restrict__ btail, unsigned int* __restrict__ bstage, int e,
    const float* __restrict__ W0, const float* __restrict__ W1,
    const float* __restrict__ W2, const float* __restrict__ Wp,
    _Float16* __restrict__ wt, _Float16* __restrict__ wt2)
{
  __shared__ int cnt[NBUCK];
  __shared__ int gstart[NBUCK];
  int t = threadIdx.x;
  int base = blockIdx.x * P1_EPB;

  // folded W-prep: one element per thread (61440 items < 196*512 threads)
  {
    int id = blockIdx.x*P1_T + t;
    if (id < 3*16384){
      int l = id >> 14, rem = id & 16383;
      int n = rem >> 7, k = rem & 127;
      const float* W = (l==0) ? W0 : (l==1) ? W1 : W2;
      wt[(size_t)l*16384 + n*128 + k] = (_Float16)W[k*128 + n];
    } else if (id < 3*16384 + 12288){
      int rem = id - 3*16384;
      int k = rem >> 5, n = rem & 31;      // Wproj[384][32] -> wt2[32][384]
      wt2[n*384 + k] = (_Float16)Wp[k*32 + n];
    }
  }

  for (int i = t; i < NBUCK; i += P1_T) cnt[i] = 0;
  __syncthreads();
  int s_[8], b_[8], dl_[8];
  #pragma unroll
  for (int j = 0; j < 8; j++){
    int i = base + j*P1_T + t;
    if (i < e){
      int d = dst[i];
      s_[j]  = src[i];
      b_[j]  = d >> 8;
      dl_[j] = d & 255;
      atomicAdd(&cnt[b_[j]], 1);
    } else b_[j] = -1;
  }
  __syncthreads();
  for (int i = t; i < NBUCK; i += P1_T){
    gstart[i] = (cnt[i] ? atomicAdd(&btail[i], cnt[i]) : 0) + i*BCAP;
    cnt[i] = 0;
  }
  __syncthreads();
  #pragma unroll
  for (int j = 0; j < 8; j++){
    if (b_[j] >= 0){
      int p = atomicAdd(&cnt[b_[j]], 1);
      bstage[(size_t)gstart[b_[j]] + p] = ((unsigned)dl_[j] << 16) | (unsigned)s_[j];
    }
  }
}

// p2: per-bucket counting sort -> CSR, bucket scan folded in (round-21).
// srcs output as uint16 (round-23) — halves srcs traffic for the smax passes.
__global__ __launch_bounds__(P2_T) void p2_csr_kernel(
    const unsigned int* __restrict__ bstage, const int* __restrict__ btail,
    int* __restrict__ rowptr, unsigned short* __restrict__ srcs)
{
  __shared__ unsigned int ebuf[BCAP];
  __shared__ unsigned short sorted[BCAP];
  __shared__ int cnt[256], ofs[256], run[256];
  __shared__ int pf[256];
  int b = blockIdx.x, t = threadIdx.x;

  if (t < 256) pf[t] = (t < NBUCK) ? btail[t] : 0;      // btail = count
  for (int i = t; i < 256; i += P2_T) cnt[i] = 0;
  __syncthreads();
  for (int off = 1; off < 256; off <<= 1){
    int v = 0;
    if (t < 256 && t >= off) v = pf[t - off];
    __syncthreads();
    if (t < 256) pf[t] += v;
    __syncthreads();
  }
  int nE = btail[b];
  int gb = pf[b] - nE;                       // exclusive prefix
  if (b == 0 && t == 0) rowptr[NNODES] = pf[NBUCK-1];
  const unsigned int* bp = bstage + (size_t)b*BCAP;

  for (int i = t; i < nE; i += P2_T){
    unsigned int v = bp[i];
    ebuf[i] = v;
    atomicAdd(&cnt[v >> 16], 1);
  }
  __syncthreads();
  if (t < 256) ofs[t] = cnt[t];
  __syncthreads();
  for (int off = 1; off < 256; off <<= 1){
    int v = 0;
    if (t < 256 && t >= off) v = ofs[t - off];
    __syncthreads();
    if (t < 256) ofs[t] += v;
    __syncthreads();
  }
  if (t < 256){
    int ex = ofs[t] - cnt[t];
    run[t] = ex;
    int node = b*256 + t;
    if (node < NNODES) rowptr[node] = gb + ex;
  }
  __syncthreads();
  for (int i = t; i < nE; i += P2_T){
    unsigned int v = ebuf[i];
    int p = atomicAdd(&run[v >> 16], 1);
    sorted[p] = (unsigned short)(v & 0xFFFFu);
  }
  __syncthreads();
  for (int i = t; i < nE; i += P2_T)
    srcs[gb + i] = sorted[i];
}

// ---------------- GEMM (h @ W) via MFMA fp16, full-K single-barrier staging ----------------
// Round-26: elv/erv written HEAD-MAJOR [4][N] so each smax quarter-XCD's elv
// working set is a 200KB plane (L2-trivial) instead of strided 800KB.
template<bool FP16IN>
__global__ __launch_bounds__(256) void gemm_feat_kernel(
    const void* __restrict__ hin, int hstride,
    const _Float16* __restrict__ Wt,   // [128 n][128 k] fp16 (pre-transposed)
    const float* __restrict__ al, const float* __restrict__ ar,
    __half* __restrict__ feat, float* __restrict__ elv, float* __restrict__ erv)
{
  __shared__ __align__(16) _Float16 Ah[TILE_R*AKPF];  // 17408 B
  __shared__ __align__(16) _Float16 Wh[HD*AKPF];      // 34816 B
  int t = threadIdx.x;
  int w = t >> 6, lane = t & 63;
  int c = lane & 15, quad = lane >> 4;
  int rbase = blockIdx.x * TILE_R;

  f32x4 acc[8];
  #pragma unroll
  for (int ct = 0; ct < 8; ct++) acc[ct] = (f32x4){0.f, 0.f, 0.f, 0.f};

  int arow = t >> 2;
  int akq  = t & 3;
  int an   = rbase + arow;
  if (FP16IN){
    const _Float16* ap = (const _Float16*)hin + (size_t)an*hstride + akq*8;
    #pragma unroll
    for (int kb = 0; kb < HD; kb += 32){
      f16x8 av = (f16x8)((_Float16)0);
      if (an < NNODES) av = *(const f16x8*)(ap + kb);
      *(f16x8*)&Ah[arow*AKPF + kb + akq*8] = av;
    }
  } else {
    const float* ap = (const float*)hin + (size_t)an*hstride + akq*8;
    #pragma unroll
    for (int kb = 0; kb < HD; kb += 32){
      float4 v0 = make_float4(0.f,0.f,0.f,0.f), v1 = v0;
      if (an < NNODES){
        v0 = *(const float4*)(ap + kb);
        v1 = *(const float4*)(ap + kb + 4);
      }
      f16x8 av;
      av[0]=(_Float16)v0.x; av[1]=(_Float16)v0.y; av[2]=(_Float16)v0.z; av[3]=(_Float16)v0.w;
      av[4]=(_Float16)v1.x; av[5]=(_Float16)v1.y; av[6]=(_Float16)v1.z; av[7]=(_Float16)v1.w;
      *(f16x8*)&Ah[arow*AKPF + kb + akq*8] = av;
    }
  }
  int wn = t >> 1;
  int wk = (t & 1) * 16;
  const _Float16* wp = Wt + wn*HD + wk;
  #pragma unroll
  for (int kb = 0; kb < HD; kb += 32){
    *(uint4*)&Wh[wn*AKPF + kb + wk]     = *(const uint4*)(wp + kb);
    *(uint4*)&Wh[wn*AKPF + kb + wk + 8] = *(const uint4*)(wp + kb + 8);
  }
  __syncthreads();

  #pragma unroll
  for (int kb = 0; kb < HD; kb += 32){
    f16x8 afrag = *(const f16x8*)&Ah[(w*16 + c)*AKPF + kb + quad*8];
    #pragma unroll
    for (int ct = 0; ct < 8; ct++){
      f16x8 bfrag = *(const f16x8*)&Wh[(ct*16 + c)*AKPF + kb + quad*8];
      acc[ct] = __builtin_amdgcn_mfma_f32_16x16x32_f16(afrag, bfrag, acc[ct], 0, 0, 0);
    }
  }

  float alv[8], arv[8];
  #pragma unroll
  for (int ct = 0; ct < 8; ct++){
    int idx = (ct >> 1)*DH + (ct & 1)*16 + c;
    alv[ct] = al[idx];
    arv[ct] = ar[idx];
  }
  #pragma unroll
  for (int r = 0; r < 4; r++){
    int n = rbase + w*16 + quad*4 + r;
    float pl[4], pr[4];
    #pragma unroll
    for (int hh = 0; hh < 4; hh++){
      pl[hh] = acc[2*hh][r]*alv[2*hh] + acc[2*hh+1][r]*alv[2*hh+1];
      pr[hh] = acc[2*hh][r]*arv[2*hh] + acc[2*hh+1][r]*arv[2*hh+1];
    }
    #pragma unroll
    for (int hh = 0; hh < 4; hh++){
      pl[hh] += __shfl_xor(pl[hh], 1); pl[hh] += __shfl_xor(pl[hh], 2);
      pl[hh] += __shfl_xor(pl[hh], 4); pl[hh] += __shfl_xor(pl[hh], 8);
      pr[hh] += __shfl_xor(pr[hh], 1); pr[hh] += __shfl_xor(pr[hh], 2);
      pr[hh] += __shfl_xor(pr[hh], 4); pr[hh] += __shfl_xor(pr[hh], 8);
    }
    if (n < NNODES){
      if (c < 4){ elv[(size_t)c*NNODES + n] = pl[c]; erv[(size_t)c*NNODES + n] = pr[c]; }
      #pragma unroll
      for (int ct = 0; ct < 8; ct++)
        feat[(size_t)n*HD + ct*16 + c] = __float2half_rn(acc[ct][r]);
    }
  }
}

// -------- fused edge-softmax + aggregation: QUARTER-ROW (HEAD) XCD SPLIT (round-26) --
// Round-25 (half split) confirmed the volume lever (-10us). Round-26: 4-way
// split aligns with HEADS: quarter q = head q = 64B of the feat row.
// quarter = blockIdx.x & 3 -> quarter q lands on XCDs {q, q+4}; per-XCD feat
// compulsory ~3.2MB -> feat fetch ~26MB (was ~44). Head-major elv [4][N]
// shrinks per-XCD elv working set to 200KB (L2-trivial). Line-visits per
// LOADB instruction: 16 groups x 64B-aligned granule = 16 — equal to the
// original round-0 kernel (1.95TB/s), NOT round-5's 64-visit TA explosion.
// 4-lane groups, 16B/lane, 3+3 pipeline (6 edges in flight), acc[8].
#define MIX2(alo, ahi, pk, aa) \
  asm("v_fma_mix_f32 %0, %2, %3, %0 op_sel:[0,0,0] op_sel_hi:[1,0,0]\n\t" \
      "v_fma_mix_f32 %1, %2, %3, %1 op_sel:[1,0,0] op_sel_hi:[1,0,0]" \
      : "+v"(alo), "+v"(ahi) : "v"(pk), "v"(aa))

__global__ __launch_bounds__(256) void smax_agg_kernel(
    const int* __restrict__ rowptr, const unsigned short* __restrict__ srcs,
    const float* __restrict__ elv, const float* __restrict__ erv,   // [4][N] head-major
    const __half* __restrict__ feat, __half* __restrict__ emb_out, int n)
{
  int bid  = blockIdx.x;
  int q    = bid & 3;                         // head/quarter -> XCDs {q, q+4}
  int node = (bid >> 2)*64 + (threadIdx.x >> 2);
  if (node >= n) return;
  int l4   = threadIdx.x & 3;
  int fo   = q*DH + l4*8;       // this lane's 8-feature (16B) slice of head q

  int s0 = rowptr[node], s1 = rowptr[node+1];
  const float* elq = elv + (size_t)q*NNODES;
  float erh = erv[(size_t)q*NNODES + node];

  float acc[8];
  #pragma unroll
  for (int j = 0; j < 8; j++) acc[j] = 0.f;
  float ssum = 0.f;

  const uint4 zq = make_uint4(0,0,0,0);

  int   sA[3], sB[3];
  uint4 qA[3], qB[3];
  float eA[3], eB[3];

#define LOADB(base, S, Q, EL)                                        \
  {                                                                  \
    _Pragma("unroll")                                                \
    for (int j = 0; j < 3; j++){                                     \
      int ee = (base) + j;                                           \
      S[j] = (ee < s1) ? (int)srcs[ee] : -1;                         \
    }                                                                \
    _Pragma("unroll")                                                \
    for (int j = 0; j < 3; j++){                                     \
      if (S[j] >= 0){                                                \
        Q[j]  = *(const uint4*)(feat + ((size_t)S[j] << 7) + fo);    \
        EL[j] = elq[S[j]];                                           \
      } else { Q[j] = zq; EL[j] = 0.f; }                             \
    }                                                                \
  }

#define ACCB(S, Q, EL)                                               \
  {                                                                  \
    _Pragma("unroll")                                                \
    for (int j = 0; j < 3; j++){                                     \
      float x = EL[j] + erh;                                         \
      float a = (S[j] >= 0) ? __expf(fmaxf(x, 0.2f*x)) : 0.f;        \
      ssum += a;                                                     \
      MIX2(acc[0], acc[1], Q[j].x, a);                               \
      MIX2(acc[2], acc[3], Q[j].y, a);                               \
      MIX2(acc[4], acc[5], Q[j].z, a);                               \
      MIX2(acc[6], acc[7], Q[j].w, a);                               \
    }                                                                \
  }

  LOADB(s0, sA, qA, eA);
  for (int e = s0; e < s1; e += 6){
    LOADB(e + 3, sB, qB, eB);
    ACCB(sA, qA, eA);
    LOADB(e + 6, sA, qA, eA);
    ACCB(sB, qB, eB);
  }
#undef LOADB
#undef ACCB

  // ssum identical across the group's 4 lanes: no reduction.
  // deg-0 node: ssum=0 -> inv=0 -> elu(0)=0 (matches reference zeros).
  float inv = (ssum > 0.f) ? 1.f / ssum : 0.f;
  __half2 hv[4];
  #pragma unroll
  for (int j = 0; j < 4; j++)
    hv[j] = __floats2half2_rn(elu(acc[2*j]*inv), elu(acc[2*j+1]*inv));
  *(uint4*)(emb_out + (size_t)node*384 + fo) = *(uint4*)&hv[0];
}

// ---------------- final projection via MFMA: emb[N,384] fp16 @ Wproj[384,32] ----------------
__global__ __launch_bounds__(256) void proj_mfma_kernel(
    const __half* __restrict__ emb, const _Float16* __restrict__ Wt2,
    float* __restrict__ out)
{
  __shared__ __align__(16) _Float16 Ah[128*136];   // 34816 B (k-chunk of 128)
  __shared__ __align__(16) _Float16 Bh[32*392];    // 25088 B (full B)
  int t = threadIdx.x;
  int w = t >> 6, lane = t & 63;
  int c = lane & 15, quad = lane >> 4;
  int rbase = blockIdx.x * 128;

  f32x4 acc[2][2];
  #pragma unroll
  for (int rt = 0; rt < 2; rt++)
    #pragma unroll
    for (int ct = 0; ct < 2; ct++) acc[rt][ct] = (f32x4){0.f,0.f,0.f,0.f};

  // stage B once: 32 rows x 384 halves = 1536 h8-chunks, 6 per thread
  #pragma unroll
  for (int i = 0; i < 6; i++){
    int idx = i*256 + t;
    int row = idx / 48;
    int q8  = idx - row*48;
    *(f16x8*)&Bh[row*392 + q8*8] = *(const f16x8*)(Wt2 + row*384 + q8*8);
  }

  for (int kc = 0; kc < 384; kc += 128){
    // stage A chunk: 128 rows x 128 halves = 2048 h8-chunks, 8 per thread
    #pragma unroll
    for (int i = 0; i < 8; i++){
      int idx = i*256 + t;
      int row = idx >> 4;
      int q   = idx & 15;
      int gr  = rbase + row;
      f16x8 v = (f16x8)((_Float16)0);
      if (gr < NNODES) v = *(const f16x8*)((const _Float16*)emb + (size_t)gr*384 + kc + q*8);
      *(f16x8*)&Ah[row*136 + q*8] = v;
    }
    __syncthreads();
    #pragma unroll
    for (int kb = 0; kb < 128; kb += 32){
      #pragma unroll
      for (int rt = 0; rt < 2; rt++){
        f16x8 afrag = *(const f16x8*)&Ah[(w*32 + rt*16 + c)*136 + kb + quad*8];
        #pragma unroll
        for (int ct = 0; ct < 2; ct++){
          f16x8 bfrag = *(const f16x8*)&Bh[(ct*16 + c)*392 + kc + kb + quad*8];
          acc[rt][ct] = __builtin_amdgcn_mfma_f32_16x16x32_f16(afrag, bfrag, acc[rt][ct], 0, 0, 0);
        }
      }
    }
    __syncthreads();
  }

  #pragma unroll
  for (int rt = 0; rt < 2; rt++)
    #pragma unroll
    for (int r = 0; r < 4; r++){
      int n = rbase + w*32 + rt*16 + quad*4 + r;
      if (n < NNODES){
        out[(size_t)n*32 + c]      = acc[rt][0][r];
        out[(size_t)n*32 + 16 + c] = acc[rt][1][r];
      }
    }
}

// ---------------- launch ----------------
extern "C" void kernel_launch(void* const* d_in, const int* in_sizes, int n_in,
                              void* d_out, int out_size, void* d_ws, size_t ws_size,
                              hipStream_t stream) {
  const float* x    = (const float*)d_in[0];
  const int*   src  = (const int*)d_in[1];
  const int*   dst  = (const int*)d_in[2];
  const float* Ws_[3]  = { (const float*)d_in[3], (const float*)d_in[6], (const float*)d_in[9]  };
  const float* als[3] = { (const float*)d_in[4], (const float*)d_in[7], (const float*)d_in[10] };
  const float* ars[3] = { (const float*)d_in[5], (const float*)d_in[8], (const float*)d_in[11] };
  const float* Wproj  = (const float*)d_in[12];
  float* out = (float*)d_out;

  char* wptr = (char*)d_ws;
  auto alloc = [&](size_t bytes) -> void* {
    void* p = (void*)wptr; wptr += (bytes + 255) & ~(size_t)255; return p;
  };
  int*            btail      = (int*)           alloc((size_t)NBUCK*4);
  unsigned*       bstage     = (unsigned*)      alloc((size_t)NBUCK*BCAP*4);
  int*            rowptr     = (int*)           alloc((size_t)(NNODES+1)*4);
  unsigned short* src_sorted = (unsigned short*)alloc((size_t)NEDGES*2);
  __half*         feat       = (__half*)        alloc((size_t)NNODES*HD*2);
  float*          elv        = (float*)         alloc((size_t)NHEADS*NNODES*4);  // head-major
  float*          erv        = (float*)         alloc((size_t)NHEADS*NNODES*4);  // head-major
  __half*         emb        = (__half*)        alloc((size_t)NNODES*384*2);
  _Float16*       wt         = (_Float16*)      alloc((size_t)3*HD*HD*2);
  _Float16*       wt2        = (_Float16*)      alloc((size_t)32*384*2);

  // btail = per-bucket COUNTS, zeroed without a kernel launch (graph-safe)
  hipMemsetAsync(btail, 0, (size_t)NBUCK*4, stream);

  // CSR build (W-prep folded into p1; scan folded into p2)
  p1_bucket_kernel<<<(NEDGES + P1_EPB - 1)/P1_EPB, P1_T, 0, stream>>>(
      src, dst, btail, bstage, NEDGES,
      Ws_[0], Ws_[1], Ws_[2], Wproj, wt, wt2);
  p2_csr_kernel<<<NBUCK, P2_T, 0, stream>>>(bstage, btail, rowptr, src_sorted);

  const int NGB = (NNODES + TILE_R - 1)/TILE_R;
  const int NSMB = ((NNODES + 63)/64) * 4;   // (node-chunk of 64) x (4 quarters)
  // layer 0: fp32 x input
  gemm_feat_kernel<false><<<NGB, 256, 0, stream>>>(
      (const void*)x, 128, wt, als[0], ars[0], feat, elv, erv);
  smax_agg_kernel<<<NSMB, 256, 0, stream>>>(rowptr, src_sorted, elv, erv,
                                            feat, emb, NNODES);
  // layers 1,2: fp16 emb input (previous layer's 128-wide slice)
  for (int l = 1; l < 3; l++){
    gemm_feat_kernel<true><<<NGB, 256, 0, stream>>>(
        (const void*)(emb + (size_t)(l-1)*128), 384,
        wt + (size_t)l*HD*HD, als[l], ars[l], feat, elv, erv);
    smax_agg_kernel<<<NSMB, 256, 0, stream>>>(rowptr, src_sorted, elv, erv,
                                              feat, emb + (size_t)l*128, NNODES);
  }

  // final projection (MFMA, K=384 in-block, direct write)
  proj_mfma_kernel<<<(NNODES + 127)/128, 256, 0, stream>>>(emb, wt2, out);
}

// Round 11
// 252.586 us; speedup vs baseline: 1.2294x; 1.2294x over previous
//
#include <hip/hip_runtime.h>
#include <hip/hip_fp16.h>
#include <math.h>

#define NNODES 50000
#define NEDGES 800000
#define HD     128      // H*D
#define NHEADS 4
#define DH     32

#define TILE_R 64       // gemm rows per block
#define AKPF   136      // full-K padded stride (halves)

// Bucketed CSR build (round-9 lesson: naive 4B random scatter = 17x write amp;
// all fine-grained scatter must happen in LDS).
#define NBUCK  196
#define BCAP   6144
#define P1_T   512
#define P1_EPB 4096
#define P2_T   512

typedef _Float16 f16x8 __attribute__((ext_vector_type(8)));
typedef float    f32x4 __attribute__((ext_vector_type(4)));

static __device__ __forceinline__ float elu(float x){ return x > 0.f ? x : __expf(x) - 1.f; }

// ---------------- CSR build, bucketed ----------------
// btail zeroed via hipMemsetAsync (holds COUNTS). W/Wproj transpose+fp16 folded
// into p1 (round-22).

__global__ __launch_bounds__(P1_T) void p1_bucket_kernel(
    const int* __restrict__ src, const int* __restrict__ dst,
    int* __restrict__ btail, unsigned int* __restrict__ bstage, int e,
    const float* __restrict__ W0, const float* __restrict__ W1,
    const float* __restrict__ W2, const float* __restrict__ Wp,
    _Float16* __restrict__ wt, _Float16* __restrict__ wt2)
{
  __shared__ int cnt[NBUCK];
  __shared__ int gstart[NBUCK];
  int t = threadIdx.x;
  int base = blockIdx.x * P1_EPB;

  // folded W-prep: one element per thread (61440 items < 196*512 threads)
  {
    int id = blockIdx.x*P1_T + t;
    if (id < 3*16384){
      int l = id >> 14, rem = id & 16383;
      int n = rem >> 7, k = rem & 127;
      const float* W = (l==0) ? W0 : (l==1) ? W1 : W2;
      wt[(size_t)l*16384 + n*128 + k] = (_Float16)W[k*128 + n];
    } else if (id < 3*16384 + 12288){
      int rem = id - 3*16384;
      int k = rem >> 5, n = rem & 31;      // Wproj[384][32] -> wt2[32][384]
      wt2[n*384 + k] = (_Float16)Wp[k*32 + n];
    }
  }

  for (int i = t; i < NBUCK; i += P1_T) cnt[i] = 0;
  __syncthreads();
  int s_[8], b_[8], dl_[8];
  #pragma unroll
  for (int j = 0; j < 8; j++){
    int i = base + j*P1_T + t;
    if (i < e){
      int d = dst[i];
      s_[j]  = src[i];
      b_[j]  = d >> 8;
      dl_[j] = d & 255;
      atomicAdd(&cnt[b_[j]], 1);
    } else b_[j] = -1;
  }
  __syncthreads();
  for (int i = t; i < NBUCK; i += P1_T){
    gstart[i] = (cnt[i] ? atomicAdd(&btail[i], cnt[i]) : 0) + i*BCAP;
    cnt[i] = 0;
  }
  __syncthreads();
  #pragma unroll
  for (int j = 0; j < 8; j++){
    if (b_[j] >= 0){
      int p = atomicAdd(&cnt[b_[j]], 1);
      bstage[(size_t)gstart[b_[j]] + p] = ((unsigned)dl_[j] << 16) | (unsigned)s_[j];
    }
  }
}

// p2: per-bucket counting sort -> CSR, bucket scan folded in (round-21).
// srcs output as uint16 (round-23) — halves srcs traffic for the smax passes.
__global__ __launch_bounds__(P2_T) void p2_csr_kernel(
    const unsigned int* __restrict__ bstage, const int* __restrict__ btail,
    int* __restrict__ rowptr, unsigned short* __restrict__ srcs)
{
  __shared__ unsigned int ebuf[BCAP];
  __shared__ unsigned short sorted[BCAP];
  __shared__ int cnt[256], ofs[256], run[256];
  __shared__ int pf[256];
  int b = blockIdx.x, t = threadIdx.x;

  if (t < 256) pf[t] = (t < NBUCK) ? btail[t] : 0;      // btail = count
  for (int i = t; i < 256; i += P2_T) cnt[i] = 0;
  __syncthreads();
  for (int off = 1; off < 256; off <<= 1){
    int v = 0;
    if (t < 256 && t >= off) v = pf[t - off];
    __syncthreads();
    if (t < 256) pf[t] += v;
    __syncthreads();
  }
  int nE = btail[b];
  int gb = pf[b] - nE;                       // exclusive prefix
  if (b == 0 && t == 0) rowptr[NNODES] = pf[NBUCK-1];
  const unsigned int* bp = bstage + (size_t)b*BCAP;

  for (int i = t; i < nE; i += P2_T){
    unsigned int v = bp[i];
    ebuf[i] = v;
    atomicAdd(&cnt[v >> 16], 1);
  }
  __syncthreads();
  if (t < 256) ofs[t] = cnt[t];
  __syncthreads();
  for (int off = 1; off < 256; off <<= 1){
    int v = 0;
    if (t < 256 && t >= off) v = ofs[t - off];
    __syncthreads();
    if (t < 256) ofs[t] += v;
    __syncthreads();
  }
  if (t < 256){
    int ex = ofs[t] - cnt[t];
    run[t] = ex;
    int node = b*256 + t;
    if (node < NNODES) rowptr[node] = gb + ex;
  }
  __syncthreads();
  for (int i = t; i < nE; i += P2_T){
    unsigned int v = ebuf[i];
    int p = atomicAdd(&run[v >> 16], 1);
    sorted[p] = (unsigned short)(v & 0xFFFFu);
  }
  __syncthreads();
  for (int i = t; i < nE; i += P2_T)
    srcs[gb + i] = sorted[i];
}

// ---------------- GEMM (h @ W) via MFMA fp16, full-K single-barrier staging ----------------
template<bool FP16IN>
__global__ __launch_bounds__(256) void gemm_feat_kernel(
    const void* __restrict__ hin, int hstride,
    const _Float16* __restrict__ Wt,   // [128 n][128 k] fp16 (pre-transposed)
    const float* __restrict__ al, const float* __restrict__ ar,
    __half* __restrict__ feat, float* __restrict__ elv, float* __restrict__ erv)
{
  __shared__ __align__(16) _Float16 Ah[TILE_R*AKPF];  // 17408 B
  __shared__ __align__(16) _Float16 Wh[HD*AKPF];      // 34816 B
  int t = threadIdx.x;
  int w = t >> 6, lane = t & 63;
  int c = lane & 15, quad = lane >> 4;
  int rbase = blockIdx.x * TILE_R;

  f32x4 acc[8];
  #pragma unroll
  for (int ct = 0; ct < 8; ct++) acc[ct] = (f32x4){0.f, 0.f, 0.f, 0.f};

  int arow = t >> 2;
  int akq  = t & 3;
  int an   = rbase + arow;
  if (FP16IN){
    const _Float16* ap = (const _Float16*)hin + (size_t)an*hstride + akq*8;
    #pragma unroll
    for (int kb = 0; kb < HD; kb += 32){
      f16x8 av = (f16x8)((_Float16)0);
      if (an < NNODES) av = *(const f16x8*)(ap + kb);
      *(f16x8*)&Ah[arow*AKPF + kb + akq*8] = av;
    }
  } else {
    const float* ap = (const float*)hin + (size_t)an*hstride + akq*8;
    #pragma unroll
    for (int kb = 0; kb < HD; kb += 32){
      float4 v0 = make_float4(0.f,0.f,0.f,0.f), v1 = v0;
      if (an < NNODES){
        v0 = *(const float4*)(ap + kb);
        v1 = *(const float4*)(ap + kb + 4);
      }
      f16x8 av;
      av[0]=(_Float16)v0.x; av[1]=(_Float16)v0.y; av[2]=(_Float16)v0.z; av[3]=(_Float16)v0.w;
      av[4]=(_Float16)v1.x; av[5]=(_Float16)v1.y; av[6]=(_Float16)v1.z; av[7]=(_Float16)v1.w;
      *(f16x8*)&Ah[arow*AKPF + kb + akq*8] = av;
    }
  }
  int wn = t >> 1;
  int wk = (t & 1) * 16;
  const _Float16* wp = Wt + wn*HD + wk;
  #pragma unroll
  for (int kb = 0; kb < HD; kb += 32){
    *(uint4*)&Wh[wn*AKPF + kb + wk]     = *(const uint4*)(wp + kb);
    *(uint4*)&Wh[wn*AKPF + kb + wk + 8] = *(const uint4*)(wp + kb + 8);
  }
  __syncthreads();

  #pragma unroll
  for (int kb = 0; kb < HD; kb += 32){
    f16x8 afrag = *(const f16x8*)&Ah[(w*16 + c)*AKPF + kb + quad*8];
    #pragma unroll
    for (int ct = 0; ct < 8; ct++){
      f16x8 bfrag = *(const f16x8*)&Wh[(ct*16 + c)*AKPF + kb + quad*8];
      acc[ct] = __builtin_amdgcn_mfma_f32_16x16x32_f16(afrag, bfrag, acc[ct], 0, 0, 0);
    }
  }

  float alv[8], arv[8];
  #pragma unroll
  for (int ct = 0; ct < 8; ct++){
    int idx = (ct >> 1)*DH + (ct & 1)*16 + c;
    alv[ct] = al[idx];
    arv[ct] = ar[idx];
  }
  #pragma unroll
  for (int r = 0; r < 4; r++){
    int n = rbase + w*16 + quad*4 + r;
    float pl[4], pr[4];
    #pragma unroll
    for (int hh = 0; hh < 4; hh++){
      pl[hh] = acc[2*hh][r]*alv[2*hh] + acc[2*hh+1][r]*alv[2*hh+1];
      pr[hh] = acc[2*hh][r]*arv[2*hh] + acc[2*hh+1][r]*arv[2*hh+1];
    }
    #pragma unroll
    for (int hh = 0; hh < 4; hh++){
      pl[hh] += __shfl_xor(pl[hh], 1); pl[hh] += __shfl_xor(pl[hh], 2);
      pl[hh] += __shfl_xor(pl[hh], 4); pl[hh] += __shfl_xor(pl[hh], 8);
      pr[hh] += __shfl_xor(pr[hh], 1); pr[hh] += __shfl_xor(pr[hh], 2);
      pr[hh] += __shfl_xor(pr[hh], 4); pr[hh] += __shfl_xor(pr[hh], 8);
    }
    if (n < NNODES){
      if (c < 4){ elv[n*NHEADS + c] = pl[c]; erv[n*NHEADS + c] = pr[c]; }
      #pragma unroll
      for (int ct = 0; ct < 8; ct++)
        feat[(size_t)n*HD + ct*16 + c] = __float2half_rn(acc[ct][r]);
    }
  }
}

// -------- fused edge-softmax + aggregation: HALF-ROW XCD SPLIT (round-25, best) ------
// Round-17/18: group-owns-node (no cross-lane reduce, replicated ssum).
// Round-23: occupancy cap reached. Round-24: ILP axis saturated.
// Round-25: split each 256B feat row into 2 x 128B halves (heads 0-1 / 2-3);
// half = blockIdx.x & 1 -> round-robin block->XCD mapping sends half-0 to even
// XCDs, half-1 to odd. -10us verified.
// Round-26 lesson (quarter/64B split): REGRESSED — fetch granule is >=128B
// (likely full 256B row): 64B quarters re-fetch the whole granule per XCD and
// pay 4x srcs. 128B halves are the FINEST granule-aligned split; this config
// is the volume minimum (~60MB compulsory at ~2-2.5TB/s fabric).
// 8-lane groups, 16B/lane, 3+3 pipeline (6 edges in flight).
#define MIX2(alo, ahi, pk, aa) \
  asm("v_fma_mix_f32 %0, %2, %3, %0 op_sel:[0,0,0] op_sel_hi:[1,0,0]\n\t" \
      "v_fma_mix_f32 %1, %2, %3, %1 op_sel:[1,0,0] op_sel_hi:[1,0,0]" \
      : "+v"(alo), "+v"(ahi) : "v"(pk), "v"(aa))

__global__ __launch_bounds__(256) void smax_agg_kernel(
    const int* __restrict__ rowptr, const unsigned short* __restrict__ srcs,
    const float* __restrict__ elv, const float* __restrict__ erv,
    const __half* __restrict__ feat, __half* __restrict__ emb_out, int n)
{
  int bid  = blockIdx.x;
  int half = bid & 1;                         // feature half -> XCD parity
  int node = (bid >> 1)*32 + (threadIdx.x >> 3);
  if (node >= n) return;
  int l8   = threadIdx.x & 7;
  int fo   = half*64 + l8*8;    // this lane's 8-feature (16B) slice
  int head = (half << 1) | (l8 >> 2);

  int s0 = rowptr[node], s1 = rowptr[node+1];
  float erh = erv[node*4 + head];

  float acc[8];
  #pragma unroll
  for (int j = 0; j < 8; j++) acc[j] = 0.f;
  float ssum = 0.f;

  const uint4 zq = make_uint4(0,0,0,0);

  int   sA[3], sB[3];
  uint4 qA[3], qB[3];
  float eA[3], eB[3];

#define LOADB(base, S, Q, EL)                                        \
  {                                                                  \
    _Pragma("unroll")                                                \
    for (int j = 0; j < 3; j++){                                     \
      int ee = (base) + j;                                           \
      S[j] = (ee < s1) ? (int)srcs[ee] : -1;                         \
    }                                                                \
    _Pragma("unroll")                                                \
    for (int j = 0; j < 3; j++){                                     \
      if (S[j] >= 0){                                                \
        Q[j]  = *(const uint4*)(feat + ((size_t)S[j] << 7) + fo);    \
        EL[j] = elv[S[j]*4 + head];                                  \
      } else { Q[j] = zq; EL[j] = 0.f; }                             \
    }                                                                \
  }

#define ACCB(S, Q, EL)                                               \
  {                                                                  \
    _Pragma("unroll")                                                \
    for (int j = 0; j < 3; j++){                                     \
      float x = EL[j] + erh;                                         \
      float a = (S[j] >= 0) ? __expf(fmaxf(x, 0.2f*x)) : 0.f;        \
      ssum += a;                                                     \
      MIX2(acc[0], acc[1], Q[j].x, a);                               \
      MIX2(acc[2], acc[3], Q[j].y, a);                               \
      MIX2(acc[4], acc[5], Q[j].z, a);                               \
      MIX2(acc[6], acc[7], Q[j].w, a);                               \
    }                                                                \
  }

  LOADB(s0, sA, qA, eA);
  for (int e = s0; e < s1; e += 6){
    LOADB(e + 3, sB, qB, eB);
    ACCB(sA, qA, eA);
    LOADB(e + 6, sA, qA, eA);
    ACCB(sB, qB, eB);
  }
#undef LOADB
#undef ACCB

  // ssum identical across the group's 8 lanes: no reduction.
  // deg-0 node: ssum=0 -> inv=0 -> elu(0)=0 (matches reference zeros).
  float inv = (ssum > 0.f) ? 1.f / ssum : 0.f;
  __half2 hv[4];
  #pragma unroll
  for (int j = 0; j < 4; j++)
    hv[j] = __floats2half2_rn(elu(acc[2*j]*inv), elu(acc[2*j+1]*inv));
  *(uint4*)(emb_out + (size_t)node*384 + fo) = *(uint4*)&hv[0];
}

// ---------------- final projection via MFMA: emb[N,384] fp16 @ Wproj[384,32] ----------------
__global__ __launch_bounds__(256) void proj_mfma_kernel(
    const __half* __restrict__ emb, const _Float16* __restrict__ Wt2,
    float* __restrict__ out)
{
  __shared__ __align__(16) _Float16 Ah[128*136];   // 34816 B (k-chunk of 128)
  __shared__ __align__(16) _Float16 Bh[32*392];    // 25088 B (full B)
  int t = threadIdx.x;
  int w = t >> 6, lane = t & 63;
  int c = lane & 15, quad = lane >> 4;
  int rbase = blockIdx.x * 128;

  f32x4 acc[2][2];
  #pragma unroll
  for (int rt = 0; rt < 2; rt++)
    #pragma unroll
    for (int ct = 0; ct < 2; ct++) acc[rt][ct] = (f32x4){0.f,0.f,0.f,0.f};

  // stage B once: 32 rows x 384 halves = 1536 h8-chunks, 6 per thread
  #pragma unroll
  for (int i = 0; i < 6; i++){
    int idx = i*256 + t;
    int row = idx / 48;
    int q8  = idx - row*48;
    *(f16x8*)&Bh[row*392 + q8*8] = *(const f16x8*)(Wt2 + row*384 + q8*8);
  }

  for (int kc = 0; kc < 384; kc += 128){
    // stage A chunk: 128 rows x 128 halves = 2048 h8-chunks, 8 per thread
    #pragma unroll
    for (int i = 0; i < 8; i++){
      int idx = i*256 + t;
      int row = idx >> 4;
      int q   = idx & 15;
      int gr  = rbase + row;
      f16x8 v = (f16x8)((_Float16)0);
      if (gr < NNODES) v = *(const f16x8*)((const _Float16*)emb + (size_t)gr*384 + kc + q*8);
      *(f16x8*)&Ah[row*136 + q*8] = v;
    }
    __syncthreads();
    #pragma unroll
    for (int kb = 0; kb < 128; kb += 32){
      #pragma unroll
      for (int rt = 0; rt < 2; rt++){
        f16x8 afrag = *(const f16x8*)&Ah[(w*32 + rt*16 + c)*136 + kb + quad*8];
        #pragma unroll
        for (int ct = 0; ct < 2; ct++){
          f16x8 bfrag = *(const f16x8*)&Bh[(ct*16 + c)*392 + kc + kb + quad*8];
          acc[rt][ct] = __builtin_amdgcn_mfma_f32_16x16x32_f16(afrag, bfrag, acc[rt][ct], 0, 0, 0);
        }
      }
    }
    __syncthreads();
  }

  #pragma unroll
  for (int rt = 0; rt < 2; rt++)
    #pragma unroll
    for (int r = 0; r < 4; r++){
      int n = rbase + w*32 + rt*16 + quad*4 + r;
      if (n < NNODES){
        out[(size_t)n*32 + c]      = acc[rt][0][r];
        out[(size_t)n*32 + 16 + c] = acc[rt][1][r];
      }
    }
}

// ---------------- launch ----------------
extern "C" void kernel_launch(void* const* d_in, const int* in_sizes, int n_in,
                              void* d_out, int out_size, void* d_ws, size_t ws_size,
                              hipStream_t stream) {
  const float* x    = (const float*)d_in[0];
  const int*   src  = (const int*)d_in[1];
  const int*   dst  = (const int*)d_in[2];
  const float* Ws_[3]  = { (const float*)d_in[3], (const float*)d_in[6], (const float*)d_in[9]  };
  const float* als[3] = { (const float*)d_in[4], (const float*)d_in[7], (const float*)d_in[10] };
  const float* ars[3] = { (const float*)d_in[5], (const float*)d_in[8], (const float*)d_in[11] };
  const float* Wproj  = (const float*)d_in[12];
  float* out = (float*)d_out;

  char* wptr = (char*)d_ws;
  auto alloc = [&](size_t bytes) -> void* {
    void* p = (void*)wptr; wptr += (bytes + 255) & ~(size_t)255; return p;
  };
  int*            btail      = (int*)           alloc((size_t)NBUCK*4);
  unsigned*       bstage     = (unsigned*)      alloc((size_t)NBUCK*BCAP*4);
  int*            rowptr     = (int*)           alloc((size_t)(NNODES+1)*4);
  unsigned short* src_sorted = (unsigned short*)alloc((size_t)NEDGES*2);
  __half*         feat       = (__half*)        alloc((size_t)NNODES*HD*2);
  float*          elv        = (float*)         alloc((size_t)NNODES*NHEADS*4);
  float*          erv        = (float*)         alloc((size_t)NNODES*NHEADS*4);
  __half*         emb        = (__half*)        alloc((size_t)NNODES*384*2);
  _Float16*       wt         = (_Float16*)      alloc((size_t)3*HD*HD*2);
  _Float16*       wt2        = (_Float16*)      alloc((size_t)32*384*2);

  // btail = per-bucket COUNTS, zeroed without a kernel launch (graph-safe)
  hipMemsetAsync(btail, 0, (size_t)NBUCK*4, stream);

  // CSR build (W-prep folded into p1; scan folded into p2)
  p1_bucket_kernel<<<(NEDGES + P1_EPB - 1)/P1_EPB, P1_T, 0, stream>>>(
      src, dst, btail, bstage, NEDGES,
      Ws_[0], Ws_[1], Ws_[2], Wproj, wt, wt2);
  p2_csr_kernel<<<NBUCK, P2_T, 0, stream>>>(bstage, btail, rowptr, src_sorted);

  const int NGB = (NNODES + TILE_R - 1)/TILE_R;
  const int NSMB = ((NNODES + 31)/32) * 2;   // (node-chunk of 32) x (2 halves)
  // layer 0: fp32 x input
  gemm_feat_kernel<false><<<NGB, 256, 0, stream>>>(
      (const void*)x, 128, wt, als[0], ars[0], feat, elv, erv);
  smax_agg_kernel<<<NSMB, 256, 0, stream>>>(rowptr, src_sorted, elv, erv,
                                            feat, emb, NNODES);
  // layers 1,2: fp16 emb input (previous layer's 128-wide slice)
  for (int l = 1; l < 3; l++){
    gemm_feat_kernel<true><<<NGB, 256, 0, stream>>>(
        (const void*)(emb + (size_t)(l-1)*128), 384,
        wt + (size_t)l*HD*HD, als[l], ars[l], feat, elv, erv);
    smax_agg_kernel<<<NSMB, 256, 0, stream>>>(rowptr, src_sorted, elv, erv,
                                              feat, emb + (size_t)l*128, NNODES);
  }

  // final projection (MFMA, K=384 in-block, direct write)
  proj_mfma_kernel<<<(NNODES + 127)/128, 256, 0, stream>>>(emb, wt2, out);
}